// Round 8
// baseline (254.516 us; speedup 1.0000x reference)
//
#include <hip/hip_runtime.h>

// R8: persistent-queue kernel with a slimmed tile body:
//  (1) defer-max (THR=8, log2 domain): common tile skips max-shuffles AND
//      O-rescale (wave-uniform branch, no setprio, no other confounds),
//  (2) interior tiles skip masking entirely (scalar lim_min test),
//  (3) 2-deep ping-pong prefetch for BOTH K and V fragments.
// Math identical to R3/R6. Prep + R1 fallback unchanged.

#define BB 4
#define QQ 1024
#define SS 2048
#define HH 32
#define DD 128
#define QT 64
#define KT 32
#define NTILES 64
#define TILE_ELEMS 4096
#define NITEMS 2048

typedef __attribute__((ext_vector_type(8))) short short8;
typedef __attribute__((ext_vector_type(4))) float f32x4;
typedef __attribute__((ext_vector_type(4))) unsigned int u32x4;
typedef __attribute__((ext_vector_type(8))) unsigned short u16x8;

__device__ __forceinline__ unsigned short f2bf(float f) {
    unsigned int u = __builtin_bit_cast(unsigned int, f);
    u += 0x7FFFu + ((u >> 16) & 1u);
    return (unsigned short)(u >> 16);
}
__device__ __forceinline__ unsigned int pk2(float a, float b) {
    return (unsigned int)f2bf(a) | ((unsigned int)f2bf(b) << 16);
}

// ---------------- prep: f32 cache/new -> bf16 fragment-ordered ws ----------------
__global__ __launch_bounds__(256)
void prep(const float* __restrict__ ks, const float* __restrict__ vs,
          const float* __restrict__ kc, const float* __restrict__ vc,
          const int* __restrict__ qlens, const int* __restrict__ clens,
          unsigned short* __restrict__ Kws, unsigned short* __restrict__ Vws)
{
    const int tile = blockIdx.x, h = blockIdx.y, b = blockIdx.z;
    const int qlen = qlens[b], clen = clens[b];
    if (tile * KT >= clen + qlen) return;
    const int tid = threadIdx.x;
    unsigned short* kout = Kws + (((size_t)b * HH + h) * NTILES + tile) * TILE_ELEMS;
    unsigned short* vout = Vws + (((size_t)b * HH + h) * NTILES + tile) * TILE_ELEMS;

    #pragma unroll
    for (int half = 0; half < 2; ++half) {
        int idx = tid * 8;
        int c = (idx >> 9) & 3, key15 = (idx >> 5) & 15, g = (idx >> 3) & 3;
        int key = tile * KT + half * 16 + key15;
        const float* src;
        if (key < clen) {
            src = kc + (((size_t)b * SS + key) * HH + h) * DD;
        } else {
            int i2 = key - clen; if (i2 > QQ - 1) i2 = QQ - 1;
            src = ks + (((size_t)b * QQ + i2) * HH + h) * DD;
        }
        int d0 = c * 32 + g * 8;
        f32x4 a0 = *(const f32x4*)&src[d0];
        f32x4 a1 = *(const f32x4*)&src[d0 + 4];
        u16x8 w;
        w[0] = f2bf(a0[0]); w[1] = f2bf(a0[1]); w[2] = f2bf(a0[2]); w[3] = f2bf(a0[3]);
        w[4] = f2bf(a1[0]); w[5] = f2bf(a1[1]); w[6] = f2bf(a1[2]); w[7] = f2bf(a1[3]);
        *(u16x8*)&kout[half * 2048 + idx] = w;
    }
    #pragma unroll
    for (int it = 0; it < 2; ++it) {
        int idx = it * 2048 + tid * 8;
        int n = (idx >> 9) & 7, lc = (idx >> 5) & 15, g = (idx >> 3) & 3;
        int d = n * 16 + lc;
        u16x8 w;
        #pragma unroll
        for (int e = 0; e < 8; ++e) {
            int key = tile * KT + g * 8 + e;
            const float* src;
            if (key < clen) {
                src = vc + (((size_t)b * SS + key) * HH + h) * DD;
            } else {
                int i2 = key - clen; if (i2 > QQ - 1) i2 = QQ - 1;
                src = vs + (((size_t)b * QQ + i2) * HH + h) * DD;
            }
            w[e] = f2bf(src[d]);
        }
        *(u16x8*)&vout[idx] = w;
    }
}

// ---- tile body: issue next-tile K+V loads first (2-deep pipeline), QK on
// resident KFC, skip-mask interior tiles, defer-max softmax, bpermute, PV on
// resident VFC.
#define TILE_BODY(T, KFC, VFC, KFN, VFN)                                        \
{                                                                               \
    const int pbase = (T) * KT;                                                 \
    const int tn = ((T) + 1 < nt) ? (T) + 1 : nt - 1;                           \
    const unsigned short* ktn = Kb + (size_t)tn * TILE_ELEMS;                   \
    const unsigned short* vtn = Vb + (size_t)tn * TILE_ELEMS;                   \
    _Pragma("unroll")                                                           \
    for (int c = 0; c < 4; ++c) {                                               \
        KFN[c]     = *(const short8*)&ktn[c * 512 + fo];                        \
        KFN[4 + c] = *(const short8*)&ktn[2048 + c * 512 + fo];                 \
    }                                                                           \
    _Pragma("unroll")                                                           \
    for (int n = 0; n < 8; ++n) VFN[n] = *(const short8*)&vtn[n * 512 + fo];    \
    f32x4 s0 = {0.f, 0.f, 0.f, 0.f}, s1 = {0.f, 0.f, 0.f, 0.f};                 \
    _Pragma("unroll")                                                           \
    for (int c = 0; c < 4; ++c) {                                               \
        s0 = __builtin_amdgcn_mfma_f32_16x16x32_bf16(KFC[c],     qf[c], s0, 0, 0, 0); \
        s1 = __builtin_amdgcn_mfma_f32_16x16x32_bf16(KFC[4 + c], qf[c], s1, 0, 0, 0); \
    }                                                                           \
    if (pbase + KT > lim_min) {                                                 \
        const int kg0 = pbase + g * 4, kg1 = kg0 + 16;                          \
        _Pragma("unroll")                                                       \
        for (int r = 0; r < 4; ++r) {                                           \
            if (kg0 + r >= lim_l) s0[r] = -3e38f;                               \
            if (kg1 + r >= lim_l) s1[r] = -3e38f;                               \
        }                                                                       \
    }                                                                           \
    float pm = fmaxf(fmaxf(fmaxf(s0[0], s0[1]), fmaxf(s0[2], s0[3])),           \
                     fmaxf(fmaxf(s1[0], s1[1]), fmaxf(s1[2], s1[3])));          \
    if (__any(pm > m_ + 8.0f)) {                                                \
        pm = fmaxf(pm, __shfl_xor(pm, 16));                                     \
        pm = fmaxf(pm, __shfl_xor(pm, 32));                                     \
        const float mn = fmaxf(m_, pm);                                         \
        const float alpha = __builtin_amdgcn_exp2f(m_ - mn);                    \
        m_ = mn;                                                                \
        l_ *= alpha;                                                            \
        _Pragma("unroll")                                                       \
        for (int n = 0; n < 8; ++n) {                                           \
            o[n][0] *= alpha; o[n][1] *= alpha;                                 \
            o[n][2] *= alpha; o[n][3] *= alpha;                                 \
        }                                                                       \
    }                                                                           \
    float p[8];                                                                 \
    _Pragma("unroll")                                                           \
    for (int r = 0; r < 4; ++r) {                                               \
        p[r]     = __builtin_amdgcn_exp2f(s0[r] - m_);                          \
        p[4 + r] = __builtin_amdgcn_exp2f(s1[r] - m_);                          \
    }                                                                           \
    l_ += ((p[0] + p[1]) + (p[2] + p[3])) + ((p[4] + p[5]) + (p[6] + p[7]));    \
    const int A0 = (int)pk2(p[0], p[1]), A1 = (int)pk2(p[2], p[3]);             \
    const int B0 = (int)pk2(p[4], p[5]), B1 = (int)pk2(p[6], p[7]);             \
    int dw0a = __builtin_amdgcn_ds_bpermute(addrE, A0);                         \
    int dw0b = __builtin_amdgcn_ds_bpermute(addrE, B0);                         \
    int dw1a = __builtin_amdgcn_ds_bpermute(addrE, A1);                         \
    int dw1b = __builtin_amdgcn_ds_bpermute(addrE, B1);                         \
    int dw2a = __builtin_amdgcn_ds_bpermute(addrO, A0);                         \
    int dw2b = __builtin_amdgcn_ds_bpermute(addrO, B0);                         \
    int dw3a = __builtin_amdgcn_ds_bpermute(addrO, A1);                         \
    int dw3b = __builtin_amdgcn_ds_bpermute(addrO, B1);                         \
    u32x4 pbw;                                                                  \
    pbw[0] = (unsigned int)(useB ? dw0b : dw0a);                                \
    pbw[1] = (unsigned int)(useB ? dw1b : dw1a);                                \
    pbw[2] = (unsigned int)(useB ? dw2b : dw2a);                                \
    pbw[3] = (unsigned int)(useB ? dw3b : dw3a);                                \
    const short8 pb = __builtin_bit_cast(short8, pbw);                          \
    _Pragma("unroll")                                                           \
    for (int n = 0; n < 8; ++n)                                                 \
        o[n] = __builtin_amdgcn_mfma_f32_16x16x32_bf16(VFC[n], pb, o[n], 0, 0, 0); \
}

// ---------------- hot: persistent blocks, atomic queue ----------------
__global__ __launch_bounds__(256)
void segattn_persist(const float* __restrict__ qs, const int* __restrict__ qlens,
                     const int* __restrict__ clens,
                     const unsigned short* __restrict__ Kws,
                     const unsigned short* __restrict__ Vws,
                     float* __restrict__ out, int* __restrict__ counter)
{
    __shared__ int s_item;
    const int tid = threadIdx.x, wave = tid >> 6, lane = tid & 63;
    const int g = lane >> 4, lc = lane & 15;
    const float psc = 0.08838834764831845f * 1.4426950408889634f;
    const int srcE = ((g & 1) << 1);
    const int addrE = ((srcE << 4) + lc) << 2;
    const int addrO = addrE + 64;
    const bool useB = (g >= 2);

    for (;;) {
        if (tid == 0) s_item = atomicAdd(counter, 1);
        __syncthreads();
        const int idx = s_item;
        __syncthreads();
        if (idx >= NITEMS) break;

        const int qt = 15 - (idx >> 7);       // heavy-first pop order (LPT)
        const int b = idx & 3, h = (idx >> 2) & 31;
        const int qlen = qlens[b], clen = clens[b];
        const int q0 = qt * QT;

        if (q0 >= qlen) {                     // fully padded tile -> zeros
            f32x4 z = {0.f, 0.f, 0.f, 0.f};
            #pragma unroll
            for (int i2 = 0; i2 < 8; ++i2) {
                int f = tid + i2 * 256;
                int r = f >> 5, d4 = f & 31;
                *(f32x4*)&out[(((size_t)b * QQ + q0 + r) * HH + h) * DD + d4 * 4] = z;
            }
            continue;
        }

        const int q = q0 + wave * 16 + lc;
        const float* qp = qs + (((size_t)b * QQ + q) * HH + h) * DD;
        short8 qf[4];
        #pragma unroll
        for (int c = 0; c < 4; ++c) {
            f32x4 a0 = *(const f32x4*)&qp[c * 32 + g * 8];
            f32x4 a1 = *(const f32x4*)&qp[c * 32 + g * 8 + 4];
            short8 t;
            t[0] = (short)f2bf(a0[0] * psc); t[1] = (short)f2bf(a0[1] * psc);
            t[2] = (short)f2bf(a0[2] * psc); t[3] = (short)f2bf(a0[3] * psc);
            t[4] = (short)f2bf(a1[0] * psc); t[5] = (short)f2bf(a1[1] * psc);
            t[6] = (short)f2bf(a1[2] * psc); t[7] = (short)f2bf(a1[3] * psc);
            qf[c] = t;
        }

        const int lim_l = (q < qlen) ? (clen + q + 1) : 0;
        // wave-uniform minimum limit: 0 if any lane of this wave is padded
        const int wq0 = q0 + (__builtin_amdgcn_readfirstlane(wave) << 4);
        const int lim_min = (wq0 + 15 < qlen) ? (clen + wq0 + 1) : 0;

        float m_ = -3e38f, l_ = 0.f;          // l_ LANE-PARTIAL
        f32x4 o[8];
        #pragma unroll
        for (int n = 0; n < 8; ++n) o[n] = (f32x4){0.f, 0.f, 0.f, 0.f};

        const int kmax = clen + min(q0 + QT, qlen);
        const int nt = (kmax + KT - 1) / KT;
        const unsigned short* Kb = Kws + ((size_t)(b * HH + h)) * NTILES * TILE_ELEMS;
        const unsigned short* Vb = Vws + ((size_t)(b * HH + h)) * NTILES * TILE_ELEMS;
        const int fo = lc * 32 + g * 8;

        short8 kfA[8], kfB[8], vfA[8], vfB[8];
        #pragma unroll
        for (int c = 0; c < 4; ++c) {
            kfA[c]     = *(const short8*)&Kb[c * 512 + fo];
            kfA[4 + c] = *(const short8*)&Kb[2048 + c * 512 + fo];
        }
        #pragma unroll
        for (int n = 0; n < 8; ++n) vfA[n] = *(const short8*)&Vb[n * 512 + fo];

        int t2 = 0;
        for (; t2 + 2 <= nt; t2 += 2) {
            TILE_BODY(t2,     kfA, vfA, kfB, vfB);
            TILE_BODY(t2 + 1, kfB, vfB, kfA, vfA);
        }
        if (t2 < nt) {
            TILE_BODY(t2, kfA, vfA, kfB, vfB);
        }

        // epilogue: reduce lane-partial l, store
        float lt = l_;
        lt += __shfl_xor(lt, 16);
        lt += __shfl_xor(lt, 32);
        const bool val = (q < qlen);
        const float inv = val ? (1.0f / lt) : 0.f;
        float* op = out + (((size_t)b * QQ + q) * HH + h) * DD + g * 4;
        #pragma unroll
        for (int n = 0; n < 8; ++n) {
            f32x4 w;
            w[0] = o[n][0] * inv; w[1] = o[n][1] * inv;
            w[2] = o[n][2] * inv; w[3] = o[n][3] * inv;
            *(f32x4*)&op[n * 16] = w;
        }
    }
}

// ---------------- R1 fallback (proven) if ws too small ----------------
__global__ __launch_bounds__(256)
void segattn(const float* __restrict__ qs, const float* __restrict__ ks,
             const float* __restrict__ vs, const float* __restrict__ kc,
             const float* __restrict__ vc, const int* __restrict__ qlens,
             const int* __restrict__ clens, float* __restrict__ out)
{
    const int qt = blockIdx.x, h = blockIdx.y, b = blockIdx.z;
    const int tid = threadIdx.x, wave = tid >> 6, lane = tid & 63;
    const int g = lane >> 4, lc = lane & 15;
    const int qlen = qlens[b], clen = clens[b];
    const int q0 = qt * QT;
    if (q0 >= qlen) {
        f32x4 z = {0.f, 0.f, 0.f, 0.f};
        #pragma unroll
        for (int i2 = 0; i2 < 8; ++i2) {
            int f = tid + i2 * 256;
            int r = f >> 5, d4 = f & 31;
            *(f32x4*)&out[(((size_t)b * QQ + q0 + r) * HH + h) * DD + d4 * 4] = z;
        }
        return;
    }
    alignas(16) __shared__ unsigned short Kl[KT * DD];
    alignas(16) __shared__ unsigned short Vl[DD * 40];
    alignas(16) __shared__ unsigned short Pl[4][16][40];
    const float psc = 0.08838834764831845f * 1.4426950408889634f;
    const int qrow = q0 + wave * 16 + lc;
    const float* qp = qs + (((size_t)b * QQ + qrow) * HH + h) * DD;
    short8 qf[4];
    #pragma unroll
    for (int c = 0; c < 4; ++c) {
        f32x4 a0 = *(const f32x4*)&qp[c * 32 + g * 8];
        f32x4 a1 = *(const f32x4*)&qp[c * 32 + g * 8 + 4];
        short8 t;
        t[0] = (short)f2bf(a0[0] * psc); t[1] = (short)f2bf(a0[1] * psc);
        t[2] = (short)f2bf(a0[2] * psc); t[3] = (short)f2bf(a0[3] * psc);
        t[4] = (short)f2bf(a1[0] * psc); t[5] = (short)f2bf(a1[1] * psc);
        t[6] = (short)f2bf(a1[2] * psc); t[7] = (short)f2bf(a1[3] * psc);
        qf[c] = t;
    }
    f32x4 o[8];
    #pragma unroll
    for (int n = 0; n < 8; ++n) o[n] = (f32x4){0.f, 0.f, 0.f, 0.f};
    float m_[4] = {-3e38f, -3e38f, -3e38f, -3e38f};
    float l_[4] = {0.f, 0.f, 0.f, 0.f};
    int lim[4];
    #pragma unroll
    for (int qq = 0; qq < 4; ++qq) {
        int i = q0 + wave * 16 + g * 4 + qq;
        lim[qq] = (i < qlen) ? (clen + i + 1) : 0;
    }
    const int kmax = clen + min(q0 + QT, qlen);
    const int nt = (kmax + KT - 1) / KT;
    for (int t = 0; t < nt; ++t) {
        const int pbase = t * KT;
        __syncthreads();
        #pragma unroll
        for (int it = 0; it < 4; ++it) {
            int f = tid + it * 256;
            int key = f >> 5, d4 = f & 31;
            int p = pbase + key;
            const float *srck, *srcv;
            if (p < clen) {
                size_t off = (((size_t)b * SS + p) * HH + h) * DD + d4 * 4;
                srck = kc + off; srcv = vc + off;
            } else {
                int idx = p - clen; if (idx > QQ - 1) idx = QQ - 1;
                size_t off = (((size_t)b * QQ + idx) * HH + h) * DD + d4 * 4;
                srck = ks + off; srcv = vs + off;
            }
            f32x4 kv = *(const f32x4*)srck;
            f32x4 vv = *(const f32x4*)srcv;
            int ei = (key * DD + d4 * 4) ^ ((key & 7) << 3);
            typedef __attribute__((ext_vector_type(4))) unsigned short u16x4;
            u16x4 kb4 = {f2bf(kv[0]), f2bf(kv[1]), f2bf(kv[2]), f2bf(kv[3])};
            *(u16x4*)&Kl[ei] = kb4;
            int d0 = d4 * 4;
            Vl[(d0 + 0) * 40 + key] = f2bf(vv[0]);
            Vl[(d0 + 1) * 40 + key] = f2bf(vv[1]);
            Vl[(d0 + 2) * 40 + key] = f2bf(vv[2]);
            Vl[(d0 + 3) * 40 + key] = f2bf(vv[3]);
        }
        __syncthreads();
        f32x4 sc0 = {0.f, 0.f, 0.f, 0.f}, sc1 = {0.f, 0.f, 0.f, 0.f};
        #pragma unroll
        for (int c = 0; c < 4; ++c) {
            int i0 = (lc * DD + c * 32 + g * 8) ^ ((lc & 7) << 3);
            int i1 = ((16 + lc) * DD + c * 32 + g * 8) ^ (((16 + lc) & 7) << 3);
            short8 k0 = *(const short8*)&Kl[i0];
            short8 k1 = *(const short8*)&Kl[i1];
            sc0 = __builtin_amdgcn_mfma_f32_16x16x32_bf16(qf[c], k0, sc0, 0, 0, 0);
            sc1 = __builtin_amdgcn_mfma_f32_16x16x32_bf16(qf[c], k1, sc1, 0, 0, 0);
        }
        float pr0[4], pr1[4];
        #pragma unroll
        for (int qq = 0; qq < 4; ++qq) {
            float s0 = sc0[qq], s1 = sc1[qq];
            if (pbase + lc >= lim[qq])      s0 = -3e38f;
            if (pbase + 16 + lc >= lim[qq]) s1 = -3e38f;
            float pm = fmaxf(s0, s1);
            #pragma unroll
            for (int d2 = 1; d2 < 16; d2 <<= 1) pm = fmaxf(pm, __shfl_xor(pm, d2));
            float mn = fmaxf(m_[qq], pm);
            float alpha = exp2f(m_[qq] - mn);
            float p0 = exp2f(s0 - mn), p1 = exp2f(s1 - mn);
            float rs = p0 + p1;
            #pragma unroll
            for (int d2 = 1; d2 < 16; d2 <<= 1) rs += __shfl_xor(rs, d2);
            l_[qq] = l_[qq] * alpha + rs;
            m_[qq] = mn;
            pr0[qq] = p0; pr1[qq] = p1;
            #pragma unroll
            for (int n = 0; n < 8; ++n) o[n][qq] *= alpha;
        }
        #pragma unroll
        for (int qq = 0; qq < 4; ++qq) {
            Pl[wave][g * 4 + qq][lc]      = f2bf(pr0[qq]);
            Pl[wave][g * 4 + qq][16 + lc] = f2bf(pr1[qq]);
        }
        short8 pf = *(const short8*)&Pl[wave][lc][g * 8];
        #pragma unroll
        for (int n = 0; n < 8; ++n) {
            short8 vf = *(const short8*)&Vl[(n * 16 + lc) * 40 + g * 8];
            o[n] = __builtin_amdgcn_mfma_f32_16x16x32_bf16(pf, vf, o[n], 0, 0, 0);
        }
    }
    #pragma unroll
    for (int qq = 0; qq < 4; ++qq) {
        int i = q0 + wave * 16 + g * 4 + qq;
        bool val = (i < qlen);
        float inv = val ? (1.0f / l_[qq]) : 0.f;
        size_t ob = (((size_t)b * QQ + i) * HH + h) * DD + lc;
        #pragma unroll
        for (int n = 0; n < 8; ++n)
            out[ob + (size_t)n * 16] = val ? o[n][qq] * inv : 0.f;
    }
}

extern "C" void kernel_launch(void* const* d_in, const int* in_sizes, int n_in,
                              void* d_out, int out_size, void* d_ws, size_t ws_size,
                              hipStream_t stream) {
    const float* qs = (const float*)d_in[0];
    const float* ks = (const float*)d_in[1];
    const float* vs = (const float*)d_in[2];
    const float* kc = (const float*)d_in[3];
    const float* vc = (const float*)d_in[4];
    const int* ql = (const int*)d_in[5];
    const int* cl = (const int*)d_in[6];
    float* o = (float*)d_out;

    const size_t kv_elems = (size_t)BB * HH * NTILES * TILE_ELEMS;
    const size_t kv_bytes = kv_elems * 2 * sizeof(unsigned short);   // 128 MiB
    const size_t need = kv_bytes + 128;

    if (ws_size >= need) {
        unsigned short* Kws = (unsigned short*)d_ws;
        unsigned short* Vws = Kws + kv_elems;
        int* counter = (int*)((char*)d_ws + kv_bytes);
        hipMemsetAsync(counter, 0, sizeof(int), stream);
        dim3 pgrid(NTILES, HH, BB), pblk(256, 1, 1);
        hipLaunchKernelGGL(prep, pgrid, pblk, 0, stream, ks, vs, kc, vc, ql, cl, Kws, Vws);
        dim3 grid(1024, 1, 1), blk(256, 1, 1);
        hipLaunchKernelGGL(segattn_persist, grid, blk, 0, stream, qs, ql, cl, Kws, Vws, o, counter);
    } else {
        dim3 grid(QQ / QT, HH, BB), blk(256, 1, 1);
        hipLaunchKernelGGL(segattn, grid, blk, 0, stream, qs, ks, vs, kc, vc, ql, cl, o);
    }
}

// Round 9
// 177.349 us; speedup vs baseline: 1.4351x; 1.4351x over previous
//
#include <hip/hip_runtime.h>

// R9: block-shared LDS staging of K/V tiles (4x cut in L2/L3 traffic vs
// per-wave fragment loads, which measured ~29 TB/s = L2 ceiling).
// - prep writes lane-linear fragment layout (lane*16B) -> conflict-free b128
// - 2-deep pipeline: regs hold tile t+1, LDS dbuf holds tile t; loads for t+2
//   issued before a RAW s_barrier (explicit lgkmcnt(0), vmcnt NOT drained)
// - softmax math identical to R8 (defer-max THR=8, interior mask skip)
// Persistent atomic queue, heavy-first. Prep + R1 fallback retained.

#define BB 4
#define QQ 1024
#define SS 2048
#define HH 32
#define DD 128
#define QT 64
#define KT 32
#define NTILES 64
#define TILE_ELEMS 4096
#define NITEMS 2048

typedef __attribute__((ext_vector_type(8))) short short8;
typedef __attribute__((ext_vector_type(4))) float f32x4;
typedef __attribute__((ext_vector_type(4))) unsigned int u32x4;
typedef __attribute__((ext_vector_type(8))) unsigned short u16x8;

__device__ __forceinline__ unsigned short f2bf(float f) {
    unsigned int u = __builtin_bit_cast(unsigned int, f);
    u += 0x7FFFu + ((u >> 16) & 1u);
    return (unsigned short)(u >> 16);
}
__device__ __forceinline__ unsigned int pk2(float a, float b) {
    return (unsigned int)f2bf(a) | ((unsigned int)f2bf(b) << 16);
}

// ---------------- prep: f32 cache/new -> bf16 lane-linear fragment ws ----------
// K tile layout: [half][c][lane][8]: off = half*2048 + c*512 + lane*8 + e
//   holds K[key = tile*32 + half*16 + (lane&15)][d = c*32 + (lane>>4)*8 + e]
// V tile layout: [n][lane][8]: off = n*512 + lane*8 + e
//   holds V[key = tile*32 + (lane>>4)*8 + e][d = n*16 + (lane&15)]
__global__ __launch_bounds__(256)
void prep(const float* __restrict__ ks, const float* __restrict__ vs,
          const float* __restrict__ kc, const float* __restrict__ vc,
          const int* __restrict__ qlens, const int* __restrict__ clens,
          unsigned short* __restrict__ Kws, unsigned short* __restrict__ Vws)
{
    const int tile = blockIdx.x, h = blockIdx.y, b = blockIdx.z;
    const int qlen = qlens[b], clen = clens[b];
    if (tile * KT >= clen + qlen) return;
    const int tid = threadIdx.x;
    unsigned short* kout = Kws + (((size_t)b * HH + h) * NTILES + tile) * TILE_ELEMS;
    unsigned short* vout = Vws + (((size_t)b * HH + h) * NTILES + tile) * TILE_ELEMS;

    #pragma unroll
    for (int half = 0; half < 2; ++half) {
        const int key15 = tid & 15, gk = (tid >> 4) & 3, c = tid >> 6;
        int key = tile * KT + half * 16 + key15;
        const float* src;
        if (key < clen) {
            src = kc + (((size_t)b * SS + key) * HH + h) * DD;
        } else {
            int i2 = key - clen; if (i2 > QQ - 1) i2 = QQ - 1;
            src = ks + (((size_t)b * QQ + i2) * HH + h) * DD;
        }
        const int d0 = c * 32 + gk * 8;
        f32x4 a0 = *(const f32x4*)&src[d0];
        f32x4 a1 = *(const f32x4*)&src[d0 + 4];
        u16x8 w;
        w[0] = f2bf(a0[0]); w[1] = f2bf(a0[1]); w[2] = f2bf(a0[2]); w[3] = f2bf(a0[3]);
        w[4] = f2bf(a1[0]); w[5] = f2bf(a1[1]); w[6] = f2bf(a1[2]); w[7] = f2bf(a1[3]);
        *(u16x8*)&kout[half * 2048 + tid * 8] = w;
    }
    #pragma unroll
    for (int it = 0; it < 2; ++it) {
        const int w_ = it * 256 + tid;
        const int lcv = w_ & 15, gv = (w_ >> 4) & 3, n = w_ >> 6;
        const int d = n * 16 + lcv;
        u16x8 w;
        #pragma unroll
        for (int e = 0; e < 8; ++e) {
            int key = tile * KT + gv * 8 + e;
            const float* src;
            if (key < clen) {
                src = vc + (((size_t)b * SS + key) * HH + h) * DD;
            } else {
                int i2 = key - clen; if (i2 > QQ - 1) i2 = QQ - 1;
                src = vs + (((size_t)b * QQ + i2) * HH + h) * DD;
            }
            w[e] = f2bf(src[d]);
        }
        *(u16x8*)&vout[w_ * 8] = w;
    }
}

// ---------------- hot: persistent queue + LDS-staged tiles ----------------
__global__ __launch_bounds__(256, 4)
void segattn_persist(const float* __restrict__ qs, const int* __restrict__ qlens,
                     const int* __restrict__ clens,
                     const unsigned short* __restrict__ Kws,
                     const unsigned short* __restrict__ Vws,
                     float* __restrict__ out, int* __restrict__ counter)
{
    __shared__ int s_item;
    alignas(16) __shared__ unsigned short KVl[2][8192];  // [buf]: K [0,4096) V [4096,8192) hw

    const int tid = threadIdx.x, wave = tid >> 6, lane = tid & 63;
    const int g = lane >> 4, lc = lane & 15;
    const float psc = 0.08838834764831845f * 1.4426950408889634f;
    const int srcE = ((g & 1) << 1);
    const int addrE = ((srcE << 4) + lc) << 2;
    const int addrO = addrE + 64;
    const bool useB = (g >= 2);
    const int whw = wave * 1024 + lane * 8;   // this wave's staging slice (halfwords)

    for (;;) {
        if (tid == 0) s_item = atomicAdd(counter, 1);
        __syncthreads();
        const int idx = s_item;
        __syncthreads();
        if (idx >= NITEMS) break;

        const int qt = 15 - (idx >> 7);       // heavy-first pop order (LPT)
        const int b = idx & 3, h = (idx >> 2) & 31;
        const int qlen = qlens[b], clen = clens[b];
        const int q0 = qt * QT;

        if (q0 >= qlen) {                     // fully padded tile -> zeros
            f32x4 z = {0.f, 0.f, 0.f, 0.f};
            #pragma unroll
            for (int i2 = 0; i2 < 8; ++i2) {
                int f = tid + i2 * 256;
                int r = f >> 5, d4 = f & 31;
                *(f32x4*)&out[(((size_t)b * QQ + q0 + r) * HH + h) * DD + d4 * 4] = z;
            }
            continue;
        }

        const int q = q0 + wave * 16 + lc;
        const float* qp = qs + (((size_t)b * QQ + q) * HH + h) * DD;
        short8 qf[4];
        #pragma unroll
        for (int c = 0; c < 4; ++c) {
            f32x4 a0 = *(const f32x4*)&qp[c * 32 + g * 8];
            f32x4 a1 = *(const f32x4*)&qp[c * 32 + g * 8 + 4];
            short8 t;
            t[0] = (short)f2bf(a0[0] * psc); t[1] = (short)f2bf(a0[1] * psc);
            t[2] = (short)f2bf(a0[2] * psc); t[3] = (short)f2bf(a0[3] * psc);
            t[4] = (short)f2bf(a1[0] * psc); t[5] = (short)f2bf(a1[1] * psc);
            t[6] = (short)f2bf(a1[2] * psc); t[7] = (short)f2bf(a1[3] * psc);
            qf[c] = t;
        }

        const int lim_l = (q < qlen) ? (clen + q + 1) : 0;
        const int wq0 = q0 + (__builtin_amdgcn_readfirstlane(wave) << 4);
        const int lim_min = (wq0 + 15 < qlen) ? (clen + wq0 + 1) : 0;

        float m_ = -3e38f, l_ = 0.f;          // l_ LANE-PARTIAL
        f32x4 o[8];
        #pragma unroll
        for (int n = 0; n < 8; ++n) o[n] = (f32x4){0.f, 0.f, 0.f, 0.f};

        const int kmax = clen + min(q0 + QT, qlen);
        const int nt = (kmax + KT - 1) / KT;
        const unsigned short* Kb = Kws + ((size_t)(b * HH + h)) * NTILES * TILE_ELEMS;
        const unsigned short* Vb = Vws + ((size_t)(b * HH + h)) * NTILES * TILE_ELEMS;

        // ---- prologue: tile 0 -> buf0 (exposed once per item)
        {
            u32x4 a0 = *(const u32x4*)&Kb[whw];
            u32x4 a1 = *(const u32x4*)&Kb[whw + 512];
            u32x4 a2 = *(const u32x4*)&Vb[whw];
            u32x4 a3 = *(const u32x4*)&Vb[whw + 512];
            *(u32x4*)&KVl[0][whw]              = a0;
            *(u32x4*)&KVl[0][whw + 512]        = a1;
            *(u32x4*)&KVl[0][4096 + whw]       = a2;
            *(u32x4*)&KVl[0][4096 + whw + 512] = a3;
            asm volatile("s_waitcnt lgkmcnt(0)" ::: "memory");
            __builtin_amdgcn_s_barrier();
            __builtin_amdgcn_sched_barrier(0);
        }
        // stage tile 1 into regs
        const int t1 = (nt > 1) ? 1 : 0;
        const unsigned short* kt1 = Kb + (size_t)t1 * TILE_ELEMS;
        const unsigned short* vt1 = Vb + (size_t)t1 * TILE_ELEMS;
        u32x4 sk0 = *(const u32x4*)&kt1[whw];
        u32x4 sk1 = *(const u32x4*)&kt1[whw + 512];
        u32x4 sv0 = *(const u32x4*)&vt1[whw];
        u32x4 sv1 = *(const u32x4*)&vt1[whw + 512];

        int cur = 0;
        for (int t = 0; t < nt; ++t) {
            const int nb = cur ^ 1;
            // publish tile t+1 (regs, loaded one phase ago) into buf[nb]
            *(u32x4*)&KVl[nb][whw]              = sk0;
            *(u32x4*)&KVl[nb][whw + 512]        = sk1;
            *(u32x4*)&KVl[nb][4096 + whw]       = sv0;
            *(u32x4*)&KVl[nb][4096 + whw + 512] = sv1;
            // issue loads for tile t+2 (NOT drained at the barrier below)
            const int t2c = (t + 2 < nt) ? t + 2 : (nt - 1);
            const unsigned short* kt2 = Kb + (size_t)t2c * TILE_ELEMS;
            const unsigned short* vt2 = Vb + (size_t)t2c * TILE_ELEMS;
            sk0 = *(const u32x4*)&kt2[whw];
            sk1 = *(const u32x4*)&kt2[whw + 512];
            sv0 = *(const u32x4*)&vt2[whw];
            sv1 = *(const u32x4*)&vt2[whw + 512];
            asm volatile("s_waitcnt lgkmcnt(0)" ::: "memory");
            __builtin_amdgcn_s_barrier();          // buf[nb] published
            __builtin_amdgcn_sched_barrier(0);

            // ---- compute tile t from KVl[cur]
            const unsigned short* Kc = &KVl[cur][0];
            const int pbase = t * KT;
            f32x4 s0 = {0.f, 0.f, 0.f, 0.f}, s1 = {0.f, 0.f, 0.f, 0.f};
            #pragma unroll
            for (int c = 0; c < 4; ++c) {
                short8 k0 = *(const short8*)&Kc[c * 512 + lane * 8];
                short8 k1 = *(const short8*)&Kc[2048 + c * 512 + lane * 8];
                s0 = __builtin_amdgcn_mfma_f32_16x16x32_bf16(k0, qf[c], s0, 0, 0, 0);
                s1 = __builtin_amdgcn_mfma_f32_16x16x32_bf16(k1, qf[c], s1, 0, 0, 0);
            }
            if (pbase + KT > lim_min) {
                const int kg0 = pbase + g * 4, kg1 = kg0 + 16;
                #pragma unroll
                for (int r = 0; r < 4; ++r) {
                    if (kg0 + r >= lim_l) s0[r] = -3e38f;
                    if (kg1 + r >= lim_l) s1[r] = -3e38f;
                }
            }
            float pm = fmaxf(fmaxf(fmaxf(s0[0], s0[1]), fmaxf(s0[2], s0[3])),
                             fmaxf(fmaxf(s1[0], s1[1]), fmaxf(s1[2], s1[3])));
            if (__any(pm > m_ + 8.0f)) {
                pm = fmaxf(pm, __shfl_xor(pm, 16));
                pm = fmaxf(pm, __shfl_xor(pm, 32));
                const float mn = fmaxf(m_, pm);
                const float alpha = __builtin_amdgcn_exp2f(m_ - mn);
                m_ = mn;
                l_ *= alpha;
                #pragma unroll
                for (int n = 0; n < 8; ++n) {
                    o[n][0] *= alpha; o[n][1] *= alpha;
                    o[n][2] *= alpha; o[n][3] *= alpha;
                }
            }
            float p[8];
            #pragma unroll
            for (int r = 0; r < 4; ++r) {
                p[r]     = __builtin_amdgcn_exp2f(s0[r] - m_);
                p[4 + r] = __builtin_amdgcn_exp2f(s1[r] - m_);
            }
            l_ += ((p[0] + p[1]) + (p[2] + p[3])) + ((p[4] + p[5]) + (p[6] + p[7]));

            const int A0 = (int)pk2(p[0], p[1]), A1 = (int)pk2(p[2], p[3]);
            const int B0 = (int)pk2(p[4], p[5]), B1 = (int)pk2(p[6], p[7]);
            int dw0a = __builtin_amdgcn_ds_bpermute(addrE, A0);
            int dw0b = __builtin_amdgcn_ds_bpermute(addrE, B0);
            int dw1a = __builtin_amdgcn_ds_bpermute(addrE, A1);
            int dw1b = __builtin_amdgcn_ds_bpermute(addrE, B1);
            int dw2a = __builtin_amdgcn_ds_bpermute(addrO, A0);
            int dw2b = __builtin_amdgcn_ds_bpermute(addrO, B0);
            int dw3a = __builtin_amdgcn_ds_bpermute(addrO, A1);
            int dw3b = __builtin_amdgcn_ds_bpermute(addrO, B1);
            u32x4 pbw;
            pbw[0] = (unsigned int)(useB ? dw0b : dw0a);
            pbw[1] = (unsigned int)(useB ? dw1b : dw1a);
            pbw[2] = (unsigned int)(useB ? dw2b : dw2a);
            pbw[3] = (unsigned int)(useB ? dw3b : dw3a);
            const short8 pb = __builtin_bit_cast(short8, pbw);

            #pragma unroll
            for (int n = 0; n < 8; ++n) {
                short8 vr = *(const short8*)&Kc[4096 + n * 512 + lane * 8];
                o[n] = __builtin_amdgcn_mfma_f32_16x16x32_bf16(vr, pb, o[n], 0, 0, 0);
            }

            asm volatile("s_waitcnt lgkmcnt(0)" ::: "memory");
            __builtin_amdgcn_s_barrier();          // all waves done reading buf[cur]
            __builtin_amdgcn_sched_barrier(0);
            cur = nb;
        }

        // epilogue: reduce lane-partial l, store
        float lt = l_;
        lt += __shfl_xor(lt, 16);
        lt += __shfl_xor(lt, 32);
        const bool val = (q < qlen);
        const float inv = val ? (1.0f / lt) : 0.f;
        float* op = out + (((size_t)b * QQ + q) * HH + h) * DD + g * 4;
        #pragma unroll
        for (int n = 0; n < 8; ++n) {
            f32x4 w;
            w[0] = o[n][0] * inv; w[1] = o[n][1] * inv;
            w[2] = o[n][2] * inv; w[3] = o[n][3] * inv;
            *(f32x4*)&op[n * 16] = w;
        }
    }
}

// ---------------- R1 fallback (proven) if ws too small ----------------
__global__ __launch_bounds__(256)
void segattn(const float* __restrict__ qs, const float* __restrict__ ks,
             const float* __restrict__ vs, const float* __restrict__ kc,
             const float* __restrict__ vc, const int* __restrict__ qlens,
             const int* __restrict__ clens, float* __restrict__ out)
{
    const int qt = blockIdx.x, h = blockIdx.y, b = blockIdx.z;
    const int tid = threadIdx.x, wave = tid >> 6, lane = tid & 63;
    const int g = lane >> 4, lc = lane & 15;
    const int qlen = qlens[b], clen = clens[b];
    const int q0 = qt * QT;
    if (q0 >= qlen) {
        f32x4 z = {0.f, 0.f, 0.f, 0.f};
        #pragma unroll
        for (int i2 = 0; i2 < 8; ++i2) {
            int f = tid + i2 * 256;
            int r = f >> 5, d4 = f & 31;
            *(f32x4*)&out[(((size_t)b * QQ + q0 + r) * HH + h) * DD + d4 * 4] = z;
        }
        return;
    }
    alignas(16) __shared__ unsigned short Kl[KT * DD];
    alignas(16) __shared__ unsigned short Vl[DD * 40];
    alignas(16) __shared__ unsigned short Pl[4][16][40];
    const float psc = 0.08838834764831845f * 1.4426950408889634f;
    const int qrow = q0 + wave * 16 + lc;
    const float* qp = qs + (((size_t)b * QQ + qrow) * HH + h) * DD;
    short8 qf[4];
    #pragma unroll
    for (int c = 0; c < 4; ++c) {
        f32x4 a0 = *(const f32x4*)&qp[c * 32 + g * 8];
        f32x4 a1 = *(const f32x4*)&qp[c * 32 + g * 8 + 4];
        short8 t;
        t[0] = (short)f2bf(a0[0] * psc); t[1] = (short)f2bf(a0[1] * psc);
        t[2] = (short)f2bf(a0[2] * psc); t[3] = (short)f2bf(a0[3] * psc);
        t[4] = (short)f2bf(a1[0] * psc); t[5] = (short)f2bf(a1[1] * psc);
        t[6] = (short)f2bf(a1[2] * psc); t[7] = (short)f2bf(a1[3] * psc);
        qf[c] = t;
    }
    f32x4 o[8];
    #pragma unroll
    for (int n = 0; n < 8; ++n) o[n] = (f32x4){0.f, 0.f, 0.f, 0.f};
    float m_[4] = {-3e38f, -3e38f, -3e38f, -3e38f};
    float l_[4] = {0.f, 0.f, 0.f, 0.f};
    int lim[4];
    #pragma unroll
    for (int qq = 0; qq < 4; ++qq) {
        int i = q0 + wave * 16 + g * 4 + qq;
        lim[qq] = (i < qlen) ? (clen + i + 1) : 0;
    }
    const int kmax = clen + min(q0 + QT, qlen);
    const int nt = (kmax + KT - 1) / KT;
    for (int t = 0; t < nt; ++t) {
        const int pbase = t * KT;
        __syncthreads();
        #pragma unroll
        for (int it = 0; it < 4; ++it) {
            int f = tid + it * 256;
            int key = f >> 5, d4 = f & 31;
            int p = pbase + key;
            const float *srck, *srcv;
            if (p < clen) {
                size_t off = (((size_t)b * SS + p) * HH + h) * DD + d4 * 4;
                srck = kc + off; srcv = vc + off;
            } else {
                int idx = p - clen; if (idx > QQ - 1) idx = QQ - 1;
                size_t off = (((size_t)b * QQ + idx) * HH + h) * DD + d4 * 4;
                srck = ks + off; srcv = vs + off;
            }
            f32x4 kv = *(const f32x4*)srck;
            f32x4 vv = *(const f32x4*)srcv;
            int ei = (key * DD + d4 * 4) ^ ((key & 7) << 3);
            typedef __attribute__((ext_vector_type(4))) unsigned short u16x4;
            u16x4 kb4 = {f2bf(kv[0]), f2bf(kv[1]), f2bf(kv[2]), f2bf(kv[3])};
            *(u16x4*)&Kl[ei] = kb4;
            int d0 = d4 * 4;
            Vl[(d0 + 0) * 40 + key] = f2bf(vv[0]);
            Vl[(d0 + 1) * 40 + key] = f2bf(vv[1]);
            Vl[(d0 + 2) * 40 + key] = f2bf(vv[2]);
            Vl[(d0 + 3) * 40 + key] = f2bf(vv[3]);
        }
        __syncthreads();
        f32x4 sc0 = {0.f, 0.f, 0.f, 0.f}, sc1 = {0.f, 0.f, 0.f, 0.f};
        #pragma unroll
        for (int c = 0; c < 4; ++c) {
            int i0 = (lc * DD + c * 32 + g * 8) ^ ((lc & 7) << 3);
            int i1 = ((16 + lc) * DD + c * 32 + g * 8) ^ (((16 + lc) & 7) << 3);
            short8 k0 = *(const short8*)&Kl[i0];
            short8 k1 = *(const short8*)&Kl[i1];
            sc0 = __builtin_amdgcn_mfma_f32_16x16x32_bf16(qf[c], k0, sc0, 0, 0, 0);
            sc1 = __builtin_amdgcn_mfma_f32_16x16x32_bf16(qf[c], k1, sc1, 0, 0, 0);
        }
        float pr0[4], pr1[4];
        #pragma unroll
        for (int qq = 0; qq < 4; ++qq) {
            float s0 = sc0[qq], s1 = sc1[qq];
            if (pbase + lc >= lim[qq])      s0 = -3e38f;
            if (pbase + 16 + lc >= lim[qq]) s1 = -3e38f;
            float pm = fmaxf(s0, s1);
            #pragma unroll
            for (int d2 = 1; d2 < 16; d2 <<= 1) pm = fmaxf(pm, __shfl_xor(pm, d2));
            float mn = fmaxf(m_[qq], pm);
            float alpha = exp2f(m_[qq] - mn);
            float p0 = exp2f(s0 - mn), p1 = exp2f(s1 - mn);
            float rs = p0 + p1;
            #pragma unroll
            for (int d2 = 1; d2 < 16; d2 <<= 1) rs += __shfl_xor(rs, d2);
            l_[qq] = l_[qq] * alpha + rs;
            m_[qq] = mn;
            pr0[qq] = p0; pr1[qq] = p1;
            #pragma unroll
            for (int n = 0; n < 8; ++n) o[n][qq] *= alpha;
        }
        #pragma unroll
        for (int qq = 0; qq < 4; ++qq) {
            Pl[wave][g * 4 + qq][lc]      = f2bf(pr0[qq]);
            Pl[wave][g * 4 + qq][16 + lc] = f2bf(pr1[qq]);
        }
        short8 pf = *(const short8*)&Pl[wave][lc][g * 8];
        #pragma unroll
        for (int n = 0; n < 8; ++n) {
            short8 vf = *(const short8*)&Vl[(n * 16 + lc) * 40 + g * 8];
            o[n] = __builtin_amdgcn_mfma_f32_16x16x32_bf16(pf, vf, o[n], 0, 0, 0);
        }
    }
    #pragma unroll
    for (int qq = 0; qq < 4; ++qq) {
        int i = q0 + wave * 16 + g * 4 + qq;
        bool val = (i < qlen);
        float inv = val ? (1.0f / l_[qq]) : 0.f;
        size_t ob = (((size_t)b * QQ + i) * HH + h) * DD + lc;
        #pragma unroll
        for (int n = 0; n < 8; ++n)
            out[ob + (size_t)n * 16] = val ? o[n][qq] * inv : 0.f;
    }
}

extern "C" void kernel_launch(void* const* d_in, const int* in_sizes, int n_in,
                              void* d_out, int out_size, void* d_ws, size_t ws_size,
                              hipStream_t stream) {
    const float* qs = (const float*)d_in[0];
    const float* ks = (const float*)d_in[1];
    const float* vs = (const float*)d_in[2];
    const float* kc = (const float*)d_in[3];
    const float* vc = (const float*)d_in[4];
    const int* ql = (const int*)d_in[5];
    const int* cl = (const int*)d_in[6];
    float* o = (float*)d_out;

    const size_t kv_elems = (size_t)BB * HH * NTILES * TILE_ELEMS;
    const size_t kv_bytes = kv_elems * 2 * sizeof(unsigned short);   // 128 MiB
    const size_t need = kv_bytes + 128;

    if (ws_size >= need) {
        unsigned short* Kws = (unsigned short*)d_ws;
        unsigned short* Vws = Kws + kv_elems;
        int* counter = (int*)((char*)d_ws + kv_bytes);
        hipMemsetAsync(counter, 0, sizeof(int), stream);
        dim3 pgrid(NTILES, HH, BB), pblk(256, 1, 1);
        hipLaunchKernelGGL(prep, pgrid, pblk, 0, stream, ks, vs, kc, vc, ql, cl, Kws, Vws);
        dim3 grid(1024, 1, 1), blk(256, 1, 1);
        hipLaunchKernelGGL(segattn_persist, grid, blk, 0, stream, qs, ql, cl, Kws, Vws, o, counter);
    } else {
        dim3 grid(QQ / QT, HH, BB), blk(256, 1, 1);
        hipLaunchKernelGGL(segattn, grid, blk, 0, stream, qs, ks, vs, kc, vc, ql, cl, o);
    }
}